// Round 7
// baseline (364.870 us; speedup 1.0000x reference)
//
#include <hip/hip_runtime.h>

typedef __bf16 bf16;
typedef __bf16 bf16x4 __attribute__((ext_vector_type(4)));
typedef __bf16 bf16x8 __attribute__((ext_vector_type(8)));
typedef float f32x4 __attribute__((ext_vector_type(4)));

constexpr int BATCH = 32;
constexpr int SEQ   = 1024;
constexpr int CDIM  = 768;
constexpr int ROWS  = BATCH * SEQ;   // 32768
constexpr int QKVC  = 3 * CDIM;      // 2304

// ---- workspace layout (bytes), ~273.3 MB total ----
constexpr size_t oWqT = 0;                                    // bf16 WqkvT [2304][768]
constexpr size_t oWpT = oWqT + (size_t)QKVC * CDIM * 2;       // bf16 WprojT [768][768]
constexpr size_t oQKV = oWpT + (size_t)CDIM * CDIM * 2;       // bf16 qkv [32768][2304]
constexpr size_t oS   = oQKV + (size_t)ROWS * QKVC * 2;       // bf16 S [32][1024][1024]
constexpr size_t oVT  = oS   + (size_t)BATCH * SEQ * SEQ * 2; // bf16 VT [32][768][1024]
constexpr size_t oInv = oVT  + (size_t)BATCH * CDIM * SEQ * 2;// f32 invsum [32768]
constexpr size_t oAO  = oQKV; // attn_out aliases qkv (q/k dead after QK^T)
constexpr size_t oXB  = oS;   // bf16(x) aliases S (dead before QK^T writes S)
constexpr size_t oPart= oWqT; // f32 partial[32768][4] aliases WqT (dead after qkv GEMM)

__device__ __forceinline__ void gld_lds16(const void* g, void* l) {
  __builtin_amdgcn_global_load_lds(
      (const __attribute__((address_space(1))) unsigned int*)g,
      (__attribute__((address_space(3))) unsigned int*)l,
      16, 0, 0);
}

// ---------- x fp32 -> bf16 ----------
__global__ __launch_bounds__(256) void f2b_kernel(const float* __restrict__ x,
                                                  bf16* __restrict__ y) {
  int i = blockIdx.x * blockDim.x + threadIdx.x;
  const float* p = x + (size_t)i * 8;
  float4 a = *(const float4*)p;
  float4 b = *(const float4*)(p + 4);
  bf16x8 o;
  o[0]=(bf16)a.x; o[1]=(bf16)a.y; o[2]=(bf16)a.z; o[3]=(bf16)a.w;
  o[4]=(bf16)b.x; o[5]=(bf16)b.y; o[6]=(bf16)b.z; o[7]=(bf16)b.w;
  *(bf16x8*)(y + (size_t)i * 8) = o;
}

// ---------- weight transpose+convert (tiled): T[n][k] = bf16(W[k][n]) ----------
__global__ __launch_bounds__(256) void wt_kernel(const float* __restrict__ W,
                                                 bf16* __restrict__ T, int N) {
  __shared__ float t[32][33];
  int k0 = blockIdx.x * 32, n0 = blockIdx.y * 32;
  int tx = threadIdx.x & 31, ty = threadIdx.x >> 5; // 32 x 8
  #pragma unroll
  for (int i = 0; i < 4; ++i)
    t[ty + i * 8][tx] = W[(size_t)(k0 + ty + i * 8) * N + n0 + tx];
  __syncthreads();
  #pragma unroll
  for (int i = 0; i < 4; ++i)
    T[(size_t)(n0 + ty + i * 8) * 768 + k0 + tx] = (bf16)t[tx][ty + i * 8];
}

// ---------- finish: inv[row] = 1 / sum_nt partial[row][nt] ----------
__global__ __launch_bounds__(256) void finish_kernel(const float* __restrict__ partial,
                                                     float* __restrict__ inv) {
  int i = blockIdx.x * 256 + threadIdx.x;
  float4 p = *(const float4*)(partial + (size_t)i * 4);
  inv[i] = 1.0f / (p.x + p.y + p.z + p.w);
}

// ============ 256x256 8-wave NT GEMM, counted-vmcnt pipeline (T3+T4) ============
// C[z][m][n] = scale*rowScale[z][m]*sum_k A[z][m][k]*B[z][n][k] + bias[n]
// BK=64; LDS = 2 dbuf x 2 half x (128rows x 64cols) x {A,B} = 128 KiB.
// Per K-tile t (buf=t&1), 4 phases; each: {ds_read quadrant; pin; stage 1
// half-tile (2 gld_lds); s_barrier; lgkmcnt(0)+pin; setprio 16xMFMA}.
// Stage slots (from LDS free-times: A-half last read P2, B-half P3):
//   P1: B0(t+1)  P2: B1(t+1)  P3: A0(t+2)  P4: A1(t+2)
// Tile end: vmcnt(4) — drains through B1(t+1), leaves A(t+2) 4 loads in
// flight (2.5-6 phases of cover) — then s_barrier (per-wave drain BEFORE
// publish, round-3 lesson). Quadrants: P1 (0,0) reads a0,b0; P2 (1,0) reads
// a1, reuses b0; P3 (1,1) reads b1, reuses a1; P4 (0,1) reuses a0,b1.
// T2 swizzle: linear LDS dest, inverse-swizzled GLOBAL chunk c8^(r&7),
// swizzled ds_read byte kb^((row&7)<<4) (rule 21).

#define DSRD_A(dst_, qm_) do {                                                   \
  _Pragma("unroll")                                                              \
  for (int i_ = 0; i_ < 4; ++i_) {                                               \
    const int row_ = wm * 128 + (qm_) * 64 + i_ * 16 + lr;                       \
    const char* rb_ = (const char*)Acur + row_ * 128;                            \
    dst_[i_][0] = *(const bf16x8*)(rb_ + ((0  + kb0) ^ swz));                    \
    dst_[i_][1] = *(const bf16x8*)(rb_ + ((64 + kb0) ^ swz));                    \
  }                                                                              \
} while (0)

#define DSRD_B(dst_, qn_) do {                                                   \
  _Pragma("unroll")                                                              \
  for (int j_ = 0; j_ < 2; ++j_) {                                               \
    const int row_ = wn * 64 + (qn_) * 32 + j_ * 16 + lr;                        \
    const char* rb_ = (const char*)Bcur + row_ * 128;                            \
    dst_[j_][0] = *(const bf16x8*)(rb_ + ((0  + kb0) ^ swz));                    \
    dst_[j_][1] = *(const bf16x8*)(rb_ + ((64 + kb0) ^ swz));                    \
  }                                                                              \
} while (0)

#define STG_A(buf_, kt_, h_) do {                                                \
  gld_lds16(Ast + (size_t)((h_) * 128 +  0) * lda + (size_t)(kt_) * 64,          \
            &LDSB[(buf_)][((h_) * 2 + 0) * 4096 + wv * 512]);                    \
  gld_lds16(Ast + (size_t)((h_) * 128 + 64) * lda + (size_t)(kt_) * 64,          \
            &LDSB[(buf_)][((h_) * 2 + 1) * 4096 + wv * 512]);                    \
} while (0)

#define STG_B(buf_, kt_, h_) do {                                                \
  gld_lds16(Bst + (size_t)((h_) * 128 +  0) * ldb + (size_t)(kt_) * 64,          \
            &LDSB[2 + (buf_)][((h_) * 2 + 0) * 4096 + wv * 512]);                \
  gld_lds16(Bst + (size_t)((h_) * 128 + 64) * ldb + (size_t)(kt_) * 64,          \
            &LDSB[2 + (buf_)][((h_) * 2 + 1) * 4096 + wv * 512]);                \
} while (0)

#define MMA16(a_, b_, mo_, no_) do {                                             \
  asm volatile("s_waitcnt lgkmcnt(0)" ::: "memory");                             \
  __builtin_amdgcn_sched_barrier(0);                                             \
  __builtin_amdgcn_s_setprio(1);                                                 \
  _Pragma("unroll")                                                              \
  for (int ks_ = 0; ks_ < 2; ++ks_)                                              \
    _Pragma("unroll")                                                            \
    for (int i_ = 0; i_ < 4; ++i_)                                               \
      _Pragma("unroll")                                                          \
      for (int j_ = 0; j_ < 2; ++j_)                                             \
        acc[(mo_) + i_][(no_) + j_] =                                            \
            __builtin_amdgcn_mfma_f32_16x16x32_bf16(a_[i_][ks_], b_[j_][ks_],    \
                acc[(mo_) + i_][(no_) + j_], 0, 0, 0);                           \
  __builtin_amdgcn_s_setprio(0);                                                 \
} while (0)

#define PIN() __builtin_amdgcn_sched_barrier(0)
#define BAR() __builtin_amdgcn_s_barrier()

template<bool OUT_BF16, bool HAS_BIAS, bool ROW_SCALE, bool FUSE_EXP, bool TR_V>
__global__ __launch_bounds__(512, 2) void gemm256(
    const bf16* __restrict__ Ap, const bf16* __restrict__ Bp, void* __restrict__ Cp,
    int K, int lda, int ldb, int ldc, int ntm, int ntn,
    long sA, long sB, long sC,
    float scale, const float* __restrict__ rowScale, long sRS,
    const float* __restrict__ bias, float* __restrict__ partial,
    bf16* __restrict__ vtout)
{
  __shared__ __align__(16) bf16 LDSB[4][256 * 64]; // [A0,A1,B0,B1], 128 KiB
  const int tid  = threadIdx.x;
  const int lane = tid & 63;
  const int wv   = tid >> 6;      // 0..7
  const int wm   = wv >> 2;       // 0..1  (128-row half)
  const int wn   = wv & 3;        // 0..3  (64-col strip)

  // XCD-chunked bijective swizzle (grid always a multiple of 8 here)
  const int total = (int)gridDim.x;
  const int chunk = total >> 3;
  const int bid   = (int)blockIdx.x;
  int sbid = (bid & 7) * chunk + (bid >> 3);
  const int pb = ntm * ntn;
  const int z  = sbid / pb;  sbid -= z * pb;
  const int mt = sbid / ntn;
  const int nt = sbid - mt * ntn;
  const int m0 = mt * 256, n0 = nt * 256;

  const bf16* A = Ap + (size_t)z * sA;
  const bf16* B = Bp + (size_t)z * sB;

  // staging map: row sr (0..63 per segment), chunk sc8; global chunk pre-swizzled
  const int sr  = tid >> 3;
  const int sc8 = tid & 7;
  const int gch = sc8 ^ (sr & 7);
  const bf16* Ast = A + (size_t)(m0 + sr) * lda + gch * 8;
  const bf16* Bst = B + (size_t)(n0 + sr) * ldb + gch * 8;

  const int lr  = lane & 15;
  const int swz = (lane & 7) << 4;
  const int kb0 = (lane >> 4) * 16;

  f32x4 acc[8][4] = {};
  const int nkt = K >> 6;

  // prologue: tile0 (A,B) + tile1 A; vmcnt(4) leaves A(1) in flight
  STG_A(0, 0, 0); STG_A(0, 0, 1);
  STG_B(0, 0, 0); STG_B(0, 0, 1);
  if (nkt > 1) {
    STG_A(1, 1, 0); STG_A(1, 1, 1);
    asm volatile("s_waitcnt vmcnt(4)" ::: "memory");
  } else {
    asm volatile("s_waitcnt vmcnt(0)" ::: "memory");
  }
  BAR(); PIN();

  bf16x8 a0[4][2], a1[4][2], b0[2][2], b1[2][2];
  for (int t = 0; t < nkt; ++t) {
    const int cur = t & 1;
    const bf16* Acur = LDSB[cur];
    const bf16* Bcur = LDSB[2 + cur];
    const bool sb = (t + 1 < nkt), sa = (t + 2 < nkt);
    // P1: quadrant (0,0)
    DSRD_A(a0, 0); DSRD_B(b0, 0);
    PIN();
    if (sb) STG_B(cur ^ 1, t + 1, 0);
    BAR();
    MMA16(a0, b0, 0, 0);
    BAR();
    // P2: quadrant (1,0) — reuse b0
    DSRD_A(a1, 1);
    PIN();
    if (sb) STG_B(cur ^ 1, t + 1, 1);
    BAR();
    MMA16(a1, b0, 4, 0);
    BAR();
    // P3: quadrant (1,1) — reuse a1
    DSRD_B(b1, 1);
    PIN();
    if (sa) STG_A(cur, t + 2, 0);
    BAR();
    MMA16(a1, b1, 4, 2);
    BAR();
    // P4: quadrant (0,1) — reuse a0, b1
    PIN();
    if (sa) STG_A(cur, t + 2, 1);
    BAR();
    MMA16(a0, b1, 0, 2);
    if (sa) asm volatile("s_waitcnt vmcnt(4)" ::: "memory"); // drain thru B(t+1)
    else    asm volatile("s_waitcnt vmcnt(0)" ::: "memory"); // epilogue tiles
    BAR();   // tile-end publish
    PIN();
  }

  // epilogue: C/D layout col=lane&15, row=(lane>>4)*4+reg (m89-verified)
  if (TR_V && nt >= 6) {
    // V block: write transposed to VT via LDS (row-major qkv store skipped)
    bf16* tile = LDSB[0];   // 256 c-rows x 512 B, XOR-swizzled; uses all 128 KiB
    __syncthreads();
    #pragma unroll
    for (int mf = 0; mf < 8; ++mf) {
      #pragma unroll
      for (int nf = 0; nf < 4; ++nf) {
        const int lm = wm * 128 + mf * 16 + (lane >> 4) * 4; // 4 consecutive m
        const int lc = wn * 64 + nf * 16 + (lane & 15);      // c within tile
        bf16x4 w;
        #pragma unroll
        for (int r = 0; r < 4; ++r) {
          float v = acc[mf][nf][r] * scale;
          if (HAS_BIAS) v += bias[n0 + lc];
          w[r] = (bf16)v;
        }
        *(bf16x4*)((char*)tile + lc * 512 + ((lm * 2) ^ ((lc & 7) << 4))) = w;
      }
    }
    __syncthreads();
    const int bz = m0 >> 10;          // batch index (256-row tile within one batch)
    const int mb = m0 & 1023;
    bf16* dst = vtout + ((size_t)bz * CDIM + (n0 - 2 * CDIM)) * SEQ + mb;
    #pragma unroll
    for (int it = 0; it < 16; ++it) {
      const int c  = (tid >> 5) + it * 16;
      const int ch = tid & 31;
      bf16x8 vv = *(const bf16x8*)((const char*)tile + c * 512 + ((ch * 16) ^ ((c & 7) << 4)));
      *(bf16x8*)(dst + (size_t)c * SEQ + ch * 8) = vv;
    }
  } else if (FUSE_EXP) {
    float rs[8][4];
    #pragma unroll
    for (int mf = 0; mf < 8; ++mf)
      #pragma unroll
      for (int r = 0; r < 4; ++r) rs[mf][r] = 0.f;
    #pragma unroll
    for (int mf = 0; mf < 8; ++mf)
      #pragma unroll
      for (int nf = 0; nf < 4; ++nf)
        #pragma unroll
        for (int r = 0; r < 4; ++r) {
          int gm = m0 + wm * 128 + mf * 16 + ((lane >> 4) * 4 + r);
          int gn = n0 + wn * 64 + nf * 16 + (lane & 15);
          float e = __expf(acc[mf][nf][r] * scale);
          ((bf16*)Cp)[(size_t)z * sC + (size_t)gm * ldc + gn] = (bf16)e;
          rs[mf][r] += e;
        }
    float* sl = (float*)LDSB;  // [4 strips][256 rows], LDS free after K-loop
    __syncthreads();
    #pragma unroll
    for (int mf = 0; mf < 8; ++mf)
      #pragma unroll
      for (int r = 0; r < 4; ++r) {
        float s = rs[mf][r];
        s += __shfl_xor(s, 1); s += __shfl_xor(s, 2);
        s += __shfl_xor(s, 4); s += __shfl_xor(s, 8);
        if ((lane & 15) == 0)
          sl[wn * 256 + wm * 128 + mf * 16 + (lane >> 4) * 4 + r] = s;
      }
    __syncthreads();
    if (tid < 256) {
      float s = sl[tid] + sl[256 + tid] + sl[512 + tid] + sl[768 + tid];
      partial[((size_t)z * SEQ + m0 + tid) * 4 + nt] = s;
    }
  } else {
    #pragma unroll
    for (int mf = 0; mf < 8; ++mf) {
      #pragma unroll
      for (int nf = 0; nf < 4; ++nf) {
        #pragma unroll
        for (int r = 0; r < 4; ++r) {
          int gm = m0 + wm * 128 + mf * 16 + ((lane >> 4) * 4 + r);
          int gn = n0 + wn * 64 + nf * 16 + (lane & 15);
          float v = acc[mf][nf][r] * scale;
          if (ROW_SCALE) v *= rowScale[(size_t)z * sRS + gm];
          if (HAS_BIAS)  v += bias[gn];
          if (OUT_BF16) ((bf16*)Cp)[(size_t)z * sC + (size_t)gm * ldc + gn] = (bf16)v;
          else          ((float*)Cp)[(size_t)z * sC + (size_t)gm * ldc + gn] = v;
        }
      }
    }
  }
}

extern "C" void kernel_launch(void* const* d_in, const int* in_sizes, int n_in,
                              void* d_out, int out_size, void* d_ws, size_t ws_size,
                              hipStream_t stream) {
  const float* x     = (const float*)d_in[0];
  const float* Wqkv  = (const float*)d_in[1];
  const float* bqkv  = (const float*)d_in[2];
  const float* Wproj = (const float*)d_in[3];
  const float* bproj = (const float*)d_in[4];
  float* out = (float*)d_out;
  char*  ws  = (char*)d_ws;

  bf16*  WqT = (bf16*)(ws + oWqT);
  bf16*  WpT = (bf16*)(ws + oWpT);
  bf16*  qkv = (bf16*)(ws + oQKV);
  bf16*  S   = (bf16*)(ws + oS);
  bf16*  VT  = (bf16*)(ws + oVT);
  float* inv = (float*)(ws + oInv);
  bf16*  AO  = (bf16*)(ws + oAO);
  bf16*  xb  = (bf16*)(ws + oXB);
  float* part= (float*)(ws + oPart);

  const float qk_scale = 1.0f / sqrtf((float)CDIM);

  // 1. conversions / transposes
  f2b_kernel<<<ROWS * CDIM / 8 / 256, 256, 0, stream>>>(x, xb);
  wt_kernel<<<dim3(768 / 32, QKVC / 32), 256, 0, stream>>>(Wqkv, WqT, QKVC);
  wt_kernel<<<dim3(768 / 32, CDIM / 32), 256, 0, stream>>>(Wproj, WpT, CDIM);

  // 2. qkv = xb @ WqT^T + b_qkv; V third written transposed to VT (TR_V)
  gemm256<true, true, false, false, true><<<(ROWS / 256) * (QKVC / 256), 512, 0, stream>>>(
      xb, WqT, qkv, CDIM, CDIM, CDIM, QKVC, ROWS / 256, QKVC / 256,
      0, 0, 0, 1.0f, nullptr, 0, bqkv, nullptr, VT);

  // 3. S = exp(q @ k^T * scale), fused row-partial sums (overwrites xb & WqT — both dead)
  gemm256<true, false, false, true, false><<<BATCH * (SEQ / 256) * (SEQ / 256), 512, 0, stream>>>(
      qkv, qkv + CDIM, S, CDIM, QKVC, QKVC, SEQ, SEQ / 256, SEQ / 256,
      (long)SEQ * QKVC, (long)SEQ * QKVC, (long)SEQ * SEQ, qk_scale, nullptr, 0, nullptr, part, nullptr);

  // 4. inv = 1/rowsum  (sums the 4 n-tile partials)
  finish_kernel<<<ROWS / 256, 256, 0, stream>>>(part, inv);

  // 5. attn_out = (expS @ VT^T) * inv[row]   [32 x 1024 x 768]
  gemm256<true, false, true, false, false><<<BATCH * (SEQ / 256) * (CDIM / 256), 512, 0, stream>>>(
      S, VT, AO, SEQ, SEQ, SEQ, CDIM, SEQ / 256, CDIM / 256,
      (long)SEQ * SEQ, (long)CDIM * SEQ, (long)SEQ * CDIM, 1.0f, inv, SEQ, nullptr, nullptr, nullptr);

  // 6. out = attn_out @ WpT^T + b_proj   [32768 x 768], fp32
  gemm256<false, true, false, false, false><<<(ROWS / 256) * (CDIM / 256), 512, 0, stream>>>(
      AO, WpT, out, CDIM, CDIM, CDIM, CDIM, ROWS / 256, CDIM / 256,
      0, 0, 0, 1.0f, nullptr, 0, bproj, nullptr, nullptr);
}

// Round 8
// 349.587 us; speedup vs baseline: 1.0437x; 1.0437x over previous
//
#include <hip/hip_runtime.h>

typedef __bf16 bf16;
typedef __bf16 bf16x4 __attribute__((ext_vector_type(4)));
typedef __bf16 bf16x8 __attribute__((ext_vector_type(8)));
typedef float f32x4 __attribute__((ext_vector_type(4)));

constexpr int BATCH = 32;
constexpr int SEQ   = 1024;
constexpr int CDIM  = 768;
constexpr int ROWS  = BATCH * SEQ;   // 32768
constexpr int QKVC  = 3 * CDIM;      // 2304

// ---- workspace layout (bytes), ~273.3 MB total ----
constexpr size_t oWqT = 0;                                    // bf16 WqkvT [2304][768]
constexpr size_t oWpT = oWqT + (size_t)QKVC * CDIM * 2;       // bf16 WprojT [768][768]
constexpr size_t oQKV = oWpT + (size_t)CDIM * CDIM * 2;       // bf16 qkv [32768][2304]
constexpr size_t oS   = oQKV + (size_t)ROWS * QKVC * 2;       // bf16 S [32][1024][1024]
constexpr size_t oVT  = oS   + (size_t)BATCH * SEQ * SEQ * 2; // bf16 VT [32][768][1024]
constexpr size_t oInv = oVT  + (size_t)BATCH * CDIM * SEQ * 2;// f32 invsum [32768]
constexpr size_t oAO  = oQKV; // attn_out aliases qkv (q/k dead after QK^T)
constexpr size_t oXB  = oS;   // bf16(x) aliases S (dead before QK^T writes S)
constexpr size_t oPart= oWqT; // f32 partial[32768][4] aliases WqT (dead after qkv GEMM)

__device__ __forceinline__ void gld_lds16(const void* g, void* l) {
  __builtin_amdgcn_global_load_lds(
      (const __attribute__((address_space(1))) unsigned int*)g,
      (__attribute__((address_space(3))) unsigned int*)l,
      16, 0, 0);
}

// ---------- x fp32 -> bf16 ----------
__global__ __launch_bounds__(256) void f2b_kernel(const float* __restrict__ x,
                                                  bf16* __restrict__ y) {
  int i = blockIdx.x * blockDim.x + threadIdx.x;
  const float* p = x + (size_t)i * 8;
  float4 a = *(const float4*)p;
  float4 b = *(const float4*)(p + 4);
  bf16x8 o;
  o[0]=(bf16)a.x; o[1]=(bf16)a.y; o[2]=(bf16)a.z; o[3]=(bf16)a.w;
  o[4]=(bf16)b.x; o[5]=(bf16)b.y; o[6]=(bf16)b.z; o[7]=(bf16)b.w;
  *(bf16x8*)(y + (size_t)i * 8) = o;
}

// ---------- weight transpose+convert (tiled): T[n][k] = bf16(W[k][n]) ----------
__global__ __launch_bounds__(256) void wt_kernel(const float* __restrict__ W,
                                                 bf16* __restrict__ T, int N) {
  __shared__ float t[32][33];
  int k0 = blockIdx.x * 32, n0 = blockIdx.y * 32;
  int tx = threadIdx.x & 31, ty = threadIdx.x >> 5; // 32 x 8
  #pragma unroll
  for (int i = 0; i < 4; ++i)
    t[ty + i * 8][tx] = W[(size_t)(k0 + ty + i * 8) * N + n0 + tx];
  __syncthreads();
  #pragma unroll
  for (int i = 0; i < 4; ++i)
    T[(size_t)(n0 + ty + i * 8) * 768 + k0 + tx] = (bf16)t[tx][ty + i * 8];
}

// ---------- finish: inv[row] = 1 / sum_nt partial[row][nt] ----------
__global__ __launch_bounds__(256) void finish_kernel(const float* __restrict__ partial,
                                                     float* __restrict__ inv) {
  int i = blockIdx.x * 256 + threadIdx.x;
  float4 p = *(const float4*)(partial + (size_t)i * 4);
  inv[i] = 1.0f / (p.x + p.y + p.z + p.w);
}

// ============ 256x256 8-wave NT GEMM, invariant-derived counted pipeline ========
// C[z][m][n] = scale*rowScale[z][m]*sum_k A[z][m][k]*B[z][n][k] + bias[n]
// BK=64; LDS [A0,A1,B0,B1] 256x64 each = 128 KiB double buffer.
// Region dataflow (wave wm reads A rows wm*128..+127 at P1(a0)/P2(a1); wave wn
// reads B rows wn*64..+63 at P1(b0)/P3(b1)):
//   A-half h of buf cur: last read end-P2  -> stage A(t+2) at P3/P4 (after midBAR)
//   B halves of buf cur: last read end-P3  -> B(t+1) goes to buf cur^1 (free all
//   of tile t), staged at P1/P2.
// One vmcnt(4) per tile (at top): in-order retirement drains A(t+1) [t-1.P3-4]
// and B(t+1) [t.P1-2], leaves A(t+2) (4 newest) flying with 4-5 phases cover.
// Then s_barrier publishes (per-wave drain BEFORE barrier — round-3 lesson).
// Tail: vmcnt(0) when sa==false (B(nkt-1) must land). 2 barriers/tile total.
// T2 swizzle: linear LDS dest, inverse-swizzled GLOBAL chunk c8^(r&7),
// swizzled ds_read byte kb^((row&7)<<4) (rule 21).

#define DSRD_A(dst_, qm_) do {                                                   \
  _Pragma("unroll")                                                              \
  for (int i_ = 0; i_ < 4; ++i_) {                                               \
    const int row_ = wm * 128 + (qm_) * 64 + i_ * 16 + lr;                       \
    const char* rb_ = (const char*)Acur + row_ * 128;                            \
    dst_[i_][0] = *(const bf16x8*)(rb_ + ((0  + kb0) ^ swz));                    \
    dst_[i_][1] = *(const bf16x8*)(rb_ + ((64 + kb0) ^ swz));                    \
  }                                                                              \
} while (0)

#define DSRD_B(dst_, qn_) do {                                                   \
  _Pragma("unroll")                                                              \
  for (int j_ = 0; j_ < 2; ++j_) {                                               \
    const int row_ = wn * 64 + (qn_) * 32 + j_ * 16 + lr;                        \
    const char* rb_ = (const char*)Bcur + row_ * 128;                            \
    dst_[j_][0] = *(const bf16x8*)(rb_ + ((0  + kb0) ^ swz));                    \
    dst_[j_][1] = *(const bf16x8*)(rb_ + ((64 + kb0) ^ swz));                    \
  }                                                                              \
} while (0)

#define STG_A(buf_, kt_, h_) do {                                                \
  gld_lds16(Ast + (size_t)((h_) * 128 +  0) * lda + (size_t)(kt_) * 64,          \
            &LDSB[(buf_)][((h_) * 2 + 0) * 4096 + wv * 512]);                    \
  gld_lds16(Ast + (size_t)((h_) * 128 + 64) * lda + (size_t)(kt_) * 64,          \
            &LDSB[(buf_)][((h_) * 2 + 1) * 4096 + wv * 512]);                    \
} while (0)

#define STG_B(buf_, kt_, h_) do {                                                \
  gld_lds16(Bst + (size_t)((h_) * 128 +  0) * ldb + (size_t)(kt_) * 64,          \
            &LDSB[2 + (buf_)][((h_) * 2 + 0) * 4096 + wv * 512]);                \
  gld_lds16(Bst + (size_t)((h_) * 128 + 64) * ldb + (size_t)(kt_) * 64,          \
            &LDSB[2 + (buf_)][((h_) * 2 + 1) * 4096 + wv * 512]);                \
} while (0)

#define MMA16(a_, b_, mo_, no_) do {                                             \
  asm volatile("s_waitcnt lgkmcnt(0)" ::: "memory");                             \
  __builtin_amdgcn_sched_barrier(0);                                             \
  __builtin_amdgcn_s_setprio(1);                                                 \
  _Pragma("unroll")                                                              \
  for (int ks_ = 0; ks_ < 2; ++ks_)                                              \
    _Pragma("unroll")                                                            \
    for (int i_ = 0; i_ < 4; ++i_)                                               \
      _Pragma("unroll")                                                          \
      for (int j_ = 0; j_ < 2; ++j_)                                             \
        acc[(mo_) + i_][(no_) + j_] =                                            \
            __builtin_amdgcn_mfma_f32_16x16x32_bf16(a_[i_][ks_], b_[j_][ks_],    \
                acc[(mo_) + i_][(no_) + j_], 0, 0, 0);                           \
  __builtin_amdgcn_s_setprio(0);                                                 \
} while (0)

#define PIN() __builtin_amdgcn_sched_barrier(0)
#define BAR() __builtin_amdgcn_s_barrier()

template<bool OUT_BF16, bool HAS_BIAS, bool ROW_SCALE, bool FUSE_EXP, bool TR_V>
__global__ __launch_bounds__(512, 2) void gemm256(
    const bf16* __restrict__ Ap, const bf16* __restrict__ Bp, void* __restrict__ Cp,
    int K, int lda, int ldb, int ldc, int ntm, int ntn,
    long sA, long sB, long sC,
    float scale, const float* __restrict__ rowScale, long sRS,
    const float* __restrict__ bias, float* __restrict__ partial,
    bf16* __restrict__ vtout)
{
  __shared__ __align__(16) bf16 LDSB[4][256 * 64]; // [A0,A1,B0,B1], 128 KiB
  const int tid  = threadIdx.x;
  const int lane = tid & 63;
  const int wv   = tid >> 6;      // 0..7
  const int wm   = wv >> 2;       // 0..1  (128-row half)
  const int wn   = wv & 3;        // 0..3  (64-col strip)

  // XCD-chunked bijective swizzle (grid always a multiple of 8 here)
  const int total = (int)gridDim.x;
  const int chunk = total >> 3;
  const int bid   = (int)blockIdx.x;
  int sbid = (bid & 7) * chunk + (bid >> 3);
  const int pb = ntm * ntn;
  const int z  = sbid / pb;  sbid -= z * pb;
  const int mt = sbid / ntn;
  const int nt = sbid - mt * ntn;
  const int m0 = mt * 256, n0 = nt * 256;

  const bf16* A = Ap + (size_t)z * sA;
  const bf16* B = Bp + (size_t)z * sB;

  // staging map: row sr (0..63 per segment), chunk sc8; global chunk pre-swizzled
  const int sr  = tid >> 3;
  const int sc8 = tid & 7;
  const int gch = sc8 ^ (sr & 7);
  const bf16* Ast = A + (size_t)(m0 + sr) * lda + gch * 8;
  const bf16* Bst = B + (size_t)(n0 + sr) * ldb + gch * 8;

  const int lr  = lane & 15;
  const int swz = (lane & 7) << 4;
  const int kb0 = (lane >> 4) * 16;

  f32x4 acc[8][4] = {};
  const int nkt = K >> 6;

  // prologue: tile0 (8 loads) then A(1) (4 loads, MUST be newest for vmcnt(4))
  STG_A(0, 0, 0); STG_A(0, 0, 1);
  STG_B(0, 0, 0); STG_B(0, 0, 1);
  if (nkt > 1) { STG_A(1, 1, 0); STG_A(1, 1, 1); }

  bf16x8 a0[4][2], a1[4][2], b0[2][2], b1[2][2];
  for (int t = 0; t < nkt; ++t) {
    const int cur = t & 1;
    const bf16* Acur = LDSB[cur];
    const bf16* Bcur = LDSB[2 + cur];
    const bool sb = (t + 1 < nkt);
    const bool sa = (t + 2 < nkt);
    // tile top: per-wave counted drain (tile t fully landed; A(t+2) may fly),
    // THEN publish barrier.
    if (sa) asm volatile("s_waitcnt vmcnt(4)" ::: "memory");
    else    asm volatile("s_waitcnt vmcnt(0)" ::: "memory");
    BAR(); PIN();
    // P1: quadrant (0,0); stage B0(t+1) into free buf cur^1
    DSRD_A(a0, 0); DSRD_B(b0, 0);
    PIN();
    if (sb) STG_B(cur ^ 1, t + 1, 0);
    MMA16(a0, b0, 0, 0);
    // P2: quadrant (1,0) — reuse b0; stage B1(t+1)
    DSRD_A(a1, 1);
    PIN();
    if (sb) STG_B(cur ^ 1, t + 1, 1);
    MMA16(a1, b0, 4, 0);
    BAR(); PIN();   // A(t) fully read by all waves -> A region of cur reusable
    // P3: quadrant (1,1) — reuse a1; stage A0(t+2) in place
    DSRD_B(b1, 1);
    PIN();
    if (sa) STG_A(cur, t + 2, 0);
    MMA16(a1, b1, 4, 2);
    // P4: quadrant (0,1) — reuse a0,b1; stage A1(t+2)
    if (sa) STG_A(cur, t + 2, 1);
    PIN();
    MMA16(a0, b1, 0, 2);
  }

  // epilogue: C/D layout col=lane&15, row=(lane>>4)*4+reg (m89-verified)
  if (TR_V && nt >= 6) {
    // V block: write transposed to VT via LDS (row-major qkv store skipped)
    bf16* tile = LDSB[0];   // 256 c-rows x 512 B, XOR-swizzled; uses all 128 KiB
    __syncthreads();
    #pragma unroll
    for (int mf = 0; mf < 8; ++mf) {
      #pragma unroll
      for (int nf = 0; nf < 4; ++nf) {
        const int lm = wm * 128 + mf * 16 + (lane >> 4) * 4; // 4 consecutive m
        const int lc = wn * 64 + nf * 16 + (lane & 15);      // c within tile
        bf16x4 w;
        #pragma unroll
        for (int r = 0; r < 4; ++r) {
          float v = acc[mf][nf][r] * scale;
          if (HAS_BIAS) v += bias[n0 + lc];
          w[r] = (bf16)v;
        }
        *(bf16x4*)((char*)tile + lc * 512 + ((lm * 2) ^ ((lc & 7) << 4))) = w;
      }
    }
    __syncthreads();
    const int bz = m0 >> 10;          // batch index (256-row tile within one batch)
    const int mb = m0 & 1023;
    bf16* dst = vtout + ((size_t)bz * CDIM + (n0 - 2 * CDIM)) * SEQ + mb;
    #pragma unroll
    for (int it = 0; it < 16; ++it) {
      const int c  = (tid >> 5) + it * 16;
      const int ch = tid & 31;
      bf16x8 vv = *(const bf16x8*)((const char*)tile + c * 512 + ((ch * 16) ^ ((c & 7) << 4)));
      *(bf16x8*)(dst + (size_t)c * SEQ + ch * 8) = vv;
    }
  } else if (FUSE_EXP) {
    float rs[8][4];
    #pragma unroll
    for (int mf = 0; mf < 8; ++mf)
      #pragma unroll
      for (int r = 0; r < 4; ++r) rs[mf][r] = 0.f;
    #pragma unroll
    for (int mf = 0; mf < 8; ++mf)
      #pragma unroll
      for (int nf = 0; nf < 4; ++nf)
        #pragma unroll
        for (int r = 0; r < 4; ++r) {
          int gm = m0 + wm * 128 + mf * 16 + ((lane >> 4) * 4 + r);
          int gn = n0 + wn * 64 + nf * 16 + (lane & 15);
          float e = __expf(acc[mf][nf][r] * scale);
          ((bf16*)Cp)[(size_t)z * sC + (size_t)gm * ldc + gn] = (bf16)e;
          rs[mf][r] += e;
        }
    float* sl = (float*)LDSB;  // [4 strips][256 rows], LDS free after K-loop
    __syncthreads();
    #pragma unroll
    for (int mf = 0; mf < 8; ++mf)
      #pragma unroll
      for (int r = 0; r < 4; ++r) {
        float s = rs[mf][r];
        s += __shfl_xor(s, 1); s += __shfl_xor(s, 2);
        s += __shfl_xor(s, 4); s += __shfl_xor(s, 8);
        if ((lane & 15) == 0)
          sl[wn * 256 + wm * 128 + mf * 16 + (lane >> 4) * 4 + r] = s;
      }
    __syncthreads();
    if (tid < 256) {
      float s = sl[tid] + sl[256 + tid] + sl[512 + tid] + sl[768 + tid];
      partial[((size_t)z * SEQ + m0 + tid) * 4 + nt] = s;
    }
  } else {
    #pragma unroll
    for (int mf = 0; mf < 8; ++mf) {
      #pragma unroll
      for (int nf = 0; nf < 4; ++nf) {
        #pragma unroll
        for (int r = 0; r < 4; ++r) {
          int gm = m0 + wm * 128 + mf * 16 + ((lane >> 4) * 4 + r);
          int gn = n0 + wn * 64 + nf * 16 + (lane & 15);
          float v = acc[mf][nf][r] * scale;
          if (ROW_SCALE) v *= rowScale[(size_t)z * sRS + gm];
          if (HAS_BIAS)  v += bias[gn];
          if (OUT_BF16) ((bf16*)Cp)[(size_t)z * sC + (size_t)gm * ldc + gn] = (bf16)v;
          else          ((float*)Cp)[(size_t)z * sC + (size_t)gm * ldc + gn] = v;
        }
      }
    }
  }
}

extern "C" void kernel_launch(void* const* d_in, const int* in_sizes, int n_in,
                              void* d_out, int out_size, void* d_ws, size_t ws_size,
                              hipStream_t stream) {
  const float* x     = (const float*)d_in[0];
  const float* Wqkv  = (const float*)d_in[1];
  const float* bqkv  = (const float*)d_in[2];
  const float* Wproj = (const float*)d_in[3];
  const float* bproj = (const float*)d_in[4];
  float* out = (float*)d_out;
  char*  ws  = (char*)d_ws;

  bf16*  WqT = (bf16*)(ws + oWqT);
  bf16*  WpT = (bf16*)(ws + oWpT);
  bf16*  qkv = (bf16*)(ws + oQKV);
  bf16*  S   = (bf16*)(ws + oS);
  bf16*  VT  = (bf16*)(ws + oVT);
  float* inv = (float*)(ws + oInv);
  bf16*  AO  = (bf16*)(ws + oAO);
  bf16*  xb  = (bf16*)(ws + oXB);
  float* part= (float*)(ws + oPart);

  const float qk_scale = 1.0f / sqrtf((float)CDIM);

  // 1. conversions / transposes
  f2b_kernel<<<ROWS * CDIM / 8 / 256, 256, 0, stream>>>(x, xb);
  wt_kernel<<<dim3(768 / 32, QKVC / 32), 256, 0, stream>>>(Wqkv, WqT, QKVC);
  wt_kernel<<<dim3(768 / 32, CDIM / 32), 256, 0, stream>>>(Wproj, WpT, CDIM);

  // 2. qkv = xb @ WqT^T + b_qkv; V third written transposed to VT (TR_V)
  gemm256<true, true, false, false, true><<<(ROWS / 256) * (QKVC / 256), 512, 0, stream>>>(
      xb, WqT, qkv, CDIM, CDIM, CDIM, QKVC, ROWS / 256, QKVC / 256,
      0, 0, 0, 1.0f, nullptr, 0, bqkv, nullptr, VT);

  // 3. S = exp(q @ k^T * scale), fused row-partial sums (overwrites xb & WqT — both dead)
  gemm256<true, false, false, true, false><<<BATCH * (SEQ / 256) * (SEQ / 256), 512, 0, stream>>>(
      qkv, qkv + CDIM, S, CDIM, QKVC, QKVC, SEQ, SEQ / 256, SEQ / 256,
      (long)SEQ * QKVC, (long)SEQ * QKVC, (long)SEQ * SEQ, qk_scale, nullptr, 0, nullptr, part, nullptr);

  // 4. inv = 1/rowsum  (sums the 4 n-tile partials)
  finish_kernel<<<ROWS / 256, 256, 0, stream>>>(part, inv);

  // 5. attn_out = (expS @ VT^T) * inv[row]   [32 x 1024 x 768]
  gemm256<true, false, true, false, false><<<BATCH * (SEQ / 256) * (CDIM / 256), 512, 0, stream>>>(
      S, VT, AO, SEQ, SEQ, SEQ, CDIM, SEQ / 256, CDIM / 256,
      (long)SEQ * SEQ, (long)CDIM * SEQ, (long)SEQ * CDIM, 1.0f, inv, SEQ, nullptr, nullptr, nullptr);

  // 6. out = attn_out @ WpT^T + b_proj   [32768 x 768], fp32
  gemm256<false, true, false, false, false><<<(ROWS / 256) * (CDIM / 256), 512, 0, stream>>>(
      AO, WpT, out, CDIM, CDIM, CDIM, CDIM, ROWS / 256, CDIM / 256,
      0, 0, 0, 1.0f, nullptr, 0, bproj, nullptr, nullptr);
}